// Round 4
// baseline (223.706 us; speedup 1.0000x reference)
//
#include <hip/hip_runtime.h>
#include <hip/hip_cooperative_groups.h>
#include <math.h>

namespace cg = cooperative_groups;

// Problem constants (match reference)
#define NTOT 8192
#define THRESH 0.5f
#define EPS_F 1e-8f

// Workspace float layout
#define OFF_BCE 0
#define OFF_CNT 1              // stored as unsigned int
#define OFF_TXY 2
#define OFF_TXX 3
#define OFF_TYY 4
#define OFF_ROWX 8
#define OFF_ROWY (OFF_ROWX + NTOT)
#define OFF_PS   (OFF_ROWY + NTOT)
#define OFF_SS   (OFF_PS + NTOT)
#define ZERO_FLOATS OFF_PS     // zero [0, OFF_PS): scalars + rowx + rowy

// Pairs tiling: 256-row i-tiles x 128-col j-tiles, looped over a fixed grid.
#define IT 256
#define JT 128
#define GRID 512               // 2 blocks/CU: trivially co-resident for cooperative launch
#define BLK 256

__device__ inline float wave_reduce(float v) {
#pragma unroll
    for (int o = 32; o > 0; o >>= 1) v += __shfl_down(v, o, 64);
    return v;
}

__global__ void __launch_bounds__(BLK) k_fused(const float* __restrict__ x,
                                               const float* __restrict__ t,
                                               const float* __restrict__ s,
                                               float* __restrict__ ws,
                                               float* __restrict__ out) {
    cg::grid_group g = cg::this_grid();
    __shared__ float pj[JT];
    __shared__ float sj[JT];
    __shared__ float accs[5];
    const int tid = threadIdx.x;
    const int gtid = blockIdx.x * BLK + tid;

    // ---- phase 0: zero accumulator region (replaces hipMemsetAsync) ----
    if (gtid < ZERO_FLOATS) ws[gtid] = 0.f;   // 131072 threads >= 16392 floats
    g.sync();

    // ---- phase 1: BCE partial sum + sigmoid + mask compaction ----
    float bce = 0.f;
    if (gtid < NTOT) {
        float xi = x[gtid], ti = t[gtid], si = s[gtid];
        bce = fmaxf(xi, 0.f) - xi * ti + log1pf(expf(-fabsf(xi)));
        if (si >= THRESH) {
            unsigned pos = atomicAdd((unsigned*)(ws + OFF_CNT), 1u);
            ws[OFF_PS + pos] = 1.f / (1.f + expf(-xi));
            ws[OFF_SS + pos] = si;
        }
    }
    if (blockIdx.x < NTOT / BLK) {
        bce = wave_reduce(bce);
        if ((tid & 63) == 0) atomicAdd(ws + OFF_BCE, bce);
    }
    g.sync();

    // ---- phase 2: all-pairs over the compacted set ----
    const int c = (int)*((unsigned*)(ws + OFF_CNT));
    const int nit = (c + IT - 1) / IT;
    const int njt = (c + JT - 1) / JT;
    const int ntiles = nit * njt;
    float t_xy = 0.f, t_xx = 0.f, t_yy = 0.f;
    for (int tile = blockIdx.x; tile < ntiles; tile += GRID) {
        int ib = tile % nit;
        int jb = tile / nit;
        int j0 = jb * JT;
        int nj = min(JT, c - j0);
        __syncthreads();                       // previous iteration done with pj/sj
        if (tid < nj) {
            pj[tid] = ws[OFF_PS + j0 + tid];
            sj[tid] = ws[OFF_SS + j0 + tid];
        }
        __syncthreads();
        int i = ib * IT + tid;
        if (i < c) {
            float pi = ws[OFF_PS + i], si = ws[OFF_SS + i];
            float rsx = 0.f, rsy = 0.f;
#pragma unroll 8
            for (int j = 0; j < nj; ++j) {
                float d1 = pi - pj[j];         // LDS broadcast read
                float d2 = si - sj[j];
                float a1 = fabsf(d1);
                float a2 = fabsf(d2);
                rsx += a1;
                rsy += a2;
                t_xy = fmaf(a1, a2, t_xy);
                t_xx = fmaf(d1, d1, t_xx);     // |d|^2 == d^2
                t_yy = fmaf(d2, d2, t_yy);
            }
            atomicAdd(ws + OFF_ROWX + i, rsx);
            atomicAdd(ws + OFF_ROWY + i, rsy);
        }
    }
    t_xy = wave_reduce(t_xy);
    t_xx = wave_reduce(t_xx);
    t_yy = wave_reduce(t_yy);
    if (tid < 3) accs[tid] = 0.f;
    __syncthreads();
    if ((tid & 63) == 0) {
        atomicAdd(&accs[0], t_xy);
        atomicAdd(&accs[1], t_xx);
        atomicAdd(&accs[2], t_yy);
    }
    __syncthreads();
    if (tid == 0) {                            // one global atomic triple per block
        atomicAdd(ws + OFF_TXY, accs[0]);
        atomicAdd(ws + OFF_TXX, accs[1]);
        atomicAdd(ws + OFF_TYY, accs[2]);
    }
    g.sync();

    // ---- phase 3: row-sum reduction + assemble (block 0 only) ----
    if (blockIdx.x == 0) {
        if (tid < 5) accs[tid] = 0.f;
        __syncthreads();
        float sx = 0, sy = 0, sxy = 0, sxx = 0, syy = 0;
        for (int i = tid; i < c; i += BLK) {
            float rx = ws[OFF_ROWX + i], ry = ws[OFF_ROWY + i];
            sx += rx;
            sy += ry;
            sxy = fmaf(rx, ry, sxy);
            sxx = fmaf(rx, rx, sxx);
            syy = fmaf(ry, ry, syy);
        }
        sx = wave_reduce(sx);
        sy = wave_reduce(sy);
        sxy = wave_reduce(sxy);
        sxx = wave_reduce(sxx);
        syy = wave_reduce(syy);
        if ((tid & 63) == 0) {
            atomicAdd(&accs[0], sx);
            atomicAdd(&accs[1], sy);
            atomicAdd(&accs[2], sxy);
            atomicAdd(&accs[3], sxx);
            atomicAdd(&accs[4], syy);
        }
        __syncthreads();
        if (tid == 0) {
            float bce_m = ws[OFF_BCE] / (float)NTOT;
            float cf = fmaxf((float)c, 1.f);
            float ic2 = 1.f / (cf * cf);
            float ic3 = ic2 / cf;
            float ic4 = ic2 * ic2;
            // masked mean-products via the dCov expansion identity
            float Vxy = ws[OFF_TXY] * ic2 - 2.f * accs[2] * ic3 + accs[0] * accs[1] * ic4;
            float Vxx = ws[OFF_TXX] * ic2 - 2.f * accs[3] * ic3 + accs[0] * accs[0] * ic4;
            float Vyy = ws[OFF_TYY] * ic2 - 2.f * accs[4] * ic3 + accs[1] * accs[1] * ic4;
            float dcor = sqrtf(fmaxf(Vxy, EPS_F)) /
                         (sqrtf(fmaxf(Vxx, EPS_F)) * sqrtf(fmaxf(Vyy, EPS_F)));
            out[0] = bce_m + (c > 0 ? dcor : 0.f);
        }
    }
}

extern "C" void kernel_launch(void* const* d_in, const int* in_sizes, int n_in,
                              void* d_out, int out_size, void* d_ws, size_t ws_size,
                              hipStream_t stream) {
    const float* x = (const float*)d_in[0];   // inputs  [8192]
    const float* t = (const float*)d_in[1];   // targets [8192]
    const float* s = (const float*)d_in[2];   // spectators [8192]
    float* ws = (float*)d_ws;
    float* out = (float*)d_out;

    void* args[] = {(void*)&x, (void*)&t, (void*)&s, (void*)&ws, (void*)&out};
    hipLaunchCooperativeKernel((const void*)k_fused, dim3(GRID), dim3(BLK),
                               args, 0, stream);
}

// Round 7
// 111.421 us; speedup vs baseline: 2.0077x; 2.0077x over previous
//
#include <hip/hip_runtime.h>
#include <math.h>

// Problem constants (match reference)
#define NTOT 8192
#define THRESH 0.5f
#define EPS_F 1e-8f

// Workspace float layout
#define OFF_BCE 0
#define OFF_CNT 1              // unsigned: selected count
#define OFF_TXY 2
#define OFF_TXX 3
#define OFF_TYY 4
#define OFF_DONE 5             // unsigned: finished live blocks
#define ZERO_SCALARS 8         // memset [0,8) floats = 32 B
#define OFF_ROWX 8
#define OFF_ROWY (OFF_ROWX + NTOT)
#define OFF_PSS  (OFF_ROWY + NTOT)   // float2 (p,s) interleaved, 2*NTOT floats

// Pairs tiling: 256-row i-tiles x 128-col j-tiles.
#define IT 256
#define JT 128
#define I_TILES_MAX (NTOT / IT)      // 32
#define J_TILES_MAX (NTOT / JT)      // 64
#define PAIR_GRID (I_TILES_MAX * J_TILES_MAX)

__device__ inline float wave_reduce(float v) {
#pragma unroll
    for (int o = 32; o > 0; o >>= 1) v += __shfl_down(v, o, 64);
    return v;
}

// Pass 1: zero row arrays (used by pass 2 only) + BCE partial + compaction.
__global__ void k_stage1(const float* __restrict__ x, const float* __restrict__ t,
                         const float* __restrict__ s, float* __restrict__ ws) {
    int i = blockIdx.x * blockDim.x + threadIdx.x;
    ws[OFF_ROWX + i] = 0.f;                    // safe: consumed next dispatch
    ws[OFF_ROWY + i] = 0.f;
    float xi = x[i], ti = t[i], si = s[i];
    float bce = fmaxf(xi, 0.f) - xi * ti + log1pf(expf(-fabsf(xi)));
    if (si >= THRESH) {
        unsigned pos = atomicAdd((unsigned*)(ws + OFF_CNT), 1u);  // wave-coalesced
        float p = 1.f / (1.f + expf(-xi));
        ((float2*)(ws + OFF_PSS))[pos] = make_float2(p, si);
    }
    bce = wave_reduce(bce);
    if ((threadIdx.x & 63) == 0) atomicAdd(ws + OFF_BCE, bce);
}

// Pass 2: all-pairs over the compacted set + fused finalize (last live block).
__global__ void __launch_bounds__(256) k_pairs(float* __restrict__ ws,
                                               float* __restrict__ out) {
    __shared__ float2 pjs[JT];
    __shared__ float accs[8];
    const int tid = threadIdx.x;
    const int c = (int)*((unsigned*)(ws + OFF_CNT));
    if (c == 0) {                              // degenerate: plain BCE
        if (blockIdx.x == 0 && tid == 0) out[0] = ws[OFF_BCE] / (float)NTOT;
        return;
    }
    const int nit = (c + IT - 1) / IT;
    const int njt = (c + JT - 1) / JT;
    const int ib = blockIdx.x & (I_TILES_MAX - 1);
    const int jb = blockIdx.x >> 5;            // / I_TILES_MAX
    if (ib >= nit || jb >= njt) return;        // uniform per block
    const int j0 = jb * JT;
    const int nj = min(JT, c - j0);
    const float2* pss = (const float2*)(ws + OFF_PSS);
    if (tid < nj) pjs[tid] = pss[j0 + tid];
    if (tid < 3) accs[tid] = 0.f;
    __syncthreads();

    float t_xy = 0.f, t_xx = 0.f, t_yy = 0.f;
    const int i = ib * IT + tid;
    if (i < c) {
        float2 me = pss[i];
        float rsx = 0.f, rsy = 0.f;
#pragma unroll 8
        for (int j = 0; j < nj; ++j) {
            float2 v = pjs[j];                 // ds_read_b64 broadcast
            float d1 = me.x - v.x;
            float d2 = me.y - v.y;
            float a1 = fabsf(d1);              // folds to abs input modifier
            float a2 = fabsf(d2);
            rsx += a1;
            rsy += a2;
            t_xy = fmaf(a1, a2, t_xy);
            t_xx = fmaf(d1, d1, t_xx);         // |d|^2 == d^2
            t_yy = fmaf(d2, d2, t_yy);
        }
        atomicAdd(ws + OFF_ROWX + i, rsx);
        atomicAdd(ws + OFF_ROWY + i, rsy);
    }
    t_xy = wave_reduce(t_xy);
    t_xx = wave_reduce(t_xx);
    t_yy = wave_reduce(t_yy);
    if ((tid & 63) == 0) {                     // per-wave -> LDS
        atomicAdd(&accs[0], t_xy);
        atomicAdd(&accs[1], t_xx);
        atomicAdd(&accs[2], t_yy);
    }
    __syncthreads();
    if (tid == 0) {                            // one global triple per block
        atomicAdd(ws + OFF_TXY, accs[0]);
        atomicAdd(ws + OFF_TXX, accs[1]);
        atomicAdd(ws + OFF_TYY, accs[2]);
    }

    // ---- last-block finalize ----
    __shared__ unsigned last;
    __threadfence();                           // release our atomics
    if (tid == 0) {
        unsigned prev = atomicAdd((unsigned*)(ws + OFF_DONE), 1u);
        last = (prev == (unsigned)(nit * njt - 1)) ? 1u : 0u;
    }
    __syncthreads();
    if (!last) return;
    __threadfence();                           // acquire others' writes

    if (tid < 5) accs[tid] = 0.f;
    __syncthreads();
    float sx = 0, sy = 0, sxy = 0, sxx = 0, syy = 0;
    for (int r = tid; r < c; r += 256) {
        float rx = ws[OFF_ROWX + r], ry = ws[OFF_ROWY + r];
        sx += rx;
        sy += ry;
        sxy = fmaf(rx, ry, sxy);
        sxx = fmaf(rx, rx, sxx);
        syy = fmaf(ry, ry, syy);
    }
    sx = wave_reduce(sx);
    sy = wave_reduce(sy);
    sxy = wave_reduce(sxy);
    sxx = wave_reduce(sxx);
    syy = wave_reduce(syy);
    if ((tid & 63) == 0) {
        atomicAdd(&accs[0], sx);
        atomicAdd(&accs[1], sy);
        atomicAdd(&accs[2], sxy);
        atomicAdd(&accs[3], sxx);
        atomicAdd(&accs[4], syy);
    }
    __syncthreads();
    if (tid == 0) {
        float bce = ws[OFF_BCE] / (float)NTOT;
        float cf = (float)c;
        float ic2 = 1.f / (cf * cf);
        float ic3 = ic2 / cf;
        float ic4 = ic2 * ic2;
        // masked mean-products via the dCov expansion identity
        float Vxy = ws[OFF_TXY] * ic2 - 2.f * accs[2] * ic3 + accs[0] * accs[1] * ic4;
        float Vxx = ws[OFF_TXX] * ic2 - 2.f * accs[3] * ic3 + accs[0] * accs[0] * ic4;
        float Vyy = ws[OFF_TYY] * ic2 - 2.f * accs[4] * ic3 + accs[1] * accs[1] * ic4;
        float dcor = sqrtf(fmaxf(Vxy, EPS_F)) /
                     (sqrtf(fmaxf(Vxx, EPS_F)) * sqrtf(fmaxf(Vyy, EPS_F)));
        out[0] = bce + dcor;
    }
}

extern "C" void kernel_launch(void* const* d_in, const int* in_sizes, int n_in,
                              void* d_out, int out_size, void* d_ws, size_t ws_size,
                              hipStream_t stream) {
    const float* x = (const float*)d_in[0];   // inputs  [8192]
    const float* t = (const float*)d_in[1];   // targets [8192]
    const float* s = (const float*)d_in[2];   // spectators [8192]
    float* ws = (float*)d_ws;
    float* out = (float*)d_out;

    hipMemsetAsync(d_ws, 0, ZERO_SCALARS * sizeof(float), stream);
    k_stage1<<<NTOT / 256, 256, 0, stream>>>(x, t, s, ws);
    k_pairs<<<PAIR_GRID, 256, 0, stream>>>(ws, out);
}

// Round 8
// 102.408 us; speedup vs baseline: 2.1844x; 1.0880x over previous
//
#include <hip/hip_runtime.h>
#include <math.h>

// Problem constants (match reference)
#define NTOT 8192
#define THRESH 0.5f
#define EPS_F 1e-8f

// Workspace float layout
#define OFF_BCE 0
#define OFF_CNT 1              // unsigned: selected count
#define OFF_TXY 2
#define OFF_TXX 3
#define OFF_TYY 4
#define OFF_SUMS 5             // 5 floats: sx, sy, sxy, sxx, syy
#define OFF_DONE 10            // unsigned: finished k_final blocks
#define ZERO_SCALARS 16        // memset [0,16) floats = 64 B
#define OFF_PSS  16                          // float2 (p,s), 2*NTOT floats
#define OFF_RXP  (OFF_PSS + 2 * NTOT)        // [J_TILES_MAX][NTOT] partial row-x
#define OFF_RYP  (OFF_RXP + 64 * NTOT)       // [J_TILES_MAX][NTOT] partial row-y

// Pairs tiling: 256-row i-tiles x 128-col j-tiles.
#define IT 256
#define JT 128
#define I_TILES_MAX (NTOT / IT)      // 32
#define J_TILES_MAX (NTOT / JT)      // 64
#define PAIR_GRID (I_TILES_MAX * J_TILES_MAX)
#define FIN_GRID (NTOT / 256)        // 32

__device__ inline float wave_reduce(float v) {
#pragma unroll
    for (int o = 32; o > 0; o >>= 1) v += __shfl_down(v, o, 64);
    return v;
}

// Pass 1: BCE partial sum + sigmoid + mask compaction.
__global__ void k_stage1(const float* __restrict__ x, const float* __restrict__ t,
                         const float* __restrict__ s, float* __restrict__ ws) {
    int i = blockIdx.x * blockDim.x + threadIdx.x;
    float xi = x[i], ti = t[i], si = s[i];
    float bce = fmaxf(xi, 0.f) - xi * ti + log1pf(expf(-fabsf(xi)));
    if (si >= THRESH) {
        unsigned pos = atomicAdd((unsigned*)(ws + OFF_CNT), 1u);  // wave-coalesced
        float p = 1.f / (1.f + expf(-xi));
        ((float2*)(ws + OFF_PSS))[pos] = make_float2(p, si);
    }
    bce = wave_reduce(bce);
    if ((threadIdx.x & 63) == 0) atomicAdd(ws + OFF_BCE, bce);
}

// Pass 2: all-pairs, ATOMIC-FREE row path.
// Block (ib,jb) exclusively owns row_part[jb][ib*IT .. ib*IT+IT): plain stores.
__global__ void __launch_bounds__(256) k_pairs(float* __restrict__ ws) {
    __shared__ float2 pjs[JT];
    __shared__ float accs[3];
    const int tid = threadIdx.x;
    const int c = (int)*((unsigned*)(ws + OFF_CNT));
    if (c == 0) return;
    const int nit = (c + IT - 1) / IT;
    const int njt = (c + JT - 1) / JT;
    const int ib = blockIdx.x & (I_TILES_MAX - 1);
    const int jb = blockIdx.x >> 5;            // / I_TILES_MAX
    if (ib >= nit || jb >= njt) return;        // uniform per block
    const int j0 = jb * JT;
    const int nj = min(JT, c - j0);
    const float2* pss = (const float2*)(ws + OFF_PSS);
    if (tid < nj) pjs[tid] = pss[j0 + tid];
    if (tid < 3) accs[tid] = 0.f;
    __syncthreads();

    float t_xy = 0.f, t_xx = 0.f, t_yy = 0.f;
    float rsx = 0.f, rsy = 0.f;
    const int i = ib * IT + tid;
    if (i < c) {
        float2 me = pss[i];
#pragma unroll 8
        for (int j = 0; j < nj; ++j) {
            float2 v = pjs[j];                 // ds_read_b64 broadcast
            float d1 = me.x - v.x;
            float d2 = me.y - v.y;
            float a1 = fabsf(d1);              // folds to abs input modifier
            float a2 = fabsf(d2);
            rsx += a1;
            rsy += a2;
            t_xy = fmaf(a1, a2, t_xy);
            t_xx = fmaf(d1, d1, t_xx);         // |d|^2 == d^2
            t_yy = fmaf(d2, d2, t_yy);
        }
    }
    // Exclusive-writer plain stores (i >= c lanes store 0 so k_final may read).
    ws[OFF_RXP + jb * NTOT + i] = rsx;
    ws[OFF_RYP + jb * NTOT + i] = rsy;

    t_xy = wave_reduce(t_xy);
    t_xx = wave_reduce(t_xx);
    t_yy = wave_reduce(t_yy);
    if ((tid & 63) == 0) {                     // per-wave -> LDS
        atomicAdd(&accs[0], t_xy);
        atomicAdd(&accs[1], t_xx);
        atomicAdd(&accs[2], t_yy);
    }
    __syncthreads();
    if (tid == 0) {                            // one global triple per block
        atomicAdd(ws + OFF_TXY, accs[0]);
        atomicAdd(ws + OFF_TXX, accs[1]);
        atomicAdd(ws + OFF_TYY, accs[2]);
    }
}

// Pass 3: reduce row partials + assemble in last-done block (32 blocks only).
__global__ void __launch_bounds__(256) k_final(float* __restrict__ ws,
                                               float* __restrict__ out) {
    __shared__ float accs[5];
    __shared__ unsigned last;
    const int tid = threadIdx.x;
    const int c = (int)*((unsigned*)(ws + OFF_CNT));
    const int njt = (c + JT - 1) / JT;
    float sx = 0, sy = 0, sxy = 0, sxx = 0, syy = 0;
    const int i = blockIdx.x * 256 + tid;
    if (i < c) {
        float rx = 0.f, ry = 0.f;
        for (int jb = 0; jb < njt; ++jb) {     // coalesced partial reduction
            rx += ws[OFF_RXP + jb * NTOT + i];
            ry += ws[OFF_RYP + jb * NTOT + i];
        }
        sx = rx;
        sy = ry;
        sxy = rx * ry;
        sxx = rx * rx;
        syy = ry * ry;
    }
    sx = wave_reduce(sx);
    sy = wave_reduce(sy);
    sxy = wave_reduce(sxy);
    sxx = wave_reduce(sxx);
    syy = wave_reduce(syy);
    if (tid < 5) accs[tid] = 0.f;
    __syncthreads();
    if ((tid & 63) == 0) {
        atomicAdd(&accs[0], sx);
        atomicAdd(&accs[1], sy);
        atomicAdd(&accs[2], sxy);
        atomicAdd(&accs[3], sxx);
        atomicAdd(&accs[4], syy);
    }
    __syncthreads();
    if (tid == 0) {
        atomicAdd(ws + OFF_SUMS + 0, accs[0]);
        atomicAdd(ws + OFF_SUMS + 1, accs[1]);
        atomicAdd(ws + OFF_SUMS + 2, accs[2]);
        atomicAdd(ws + OFF_SUMS + 3, accs[3]);
        atomicAdd(ws + OFF_SUMS + 4, accs[4]);
    }
    __threadfence();                           // release (32 blocks only)
    if (tid == 0) {
        unsigned prev = atomicAdd((unsigned*)(ws + OFF_DONE), 1u);
        last = (prev == FIN_GRID - 1) ? 1u : 0u;
    }
    __syncthreads();
    if (!last) return;
    __threadfence();                           // acquire
    if (tid == 0) {
        float bce = ws[OFF_BCE] / (float)NTOT;
        if (c == 0) { out[0] = bce; return; }
        float cf = (float)c;
        float ic2 = 1.f / (cf * cf);
        float ic3 = ic2 / cf;
        float ic4 = ic2 * ic2;
        float Sx = ws[OFF_SUMS + 0], Sy = ws[OFF_SUMS + 1];
        // masked mean-products via the dCov expansion identity
        float Vxy = ws[OFF_TXY] * ic2 - 2.f * ws[OFF_SUMS + 2] * ic3 + Sx * Sy * ic4;
        float Vxx = ws[OFF_TXX] * ic2 - 2.f * ws[OFF_SUMS + 3] * ic3 + Sx * Sx * ic4;
        float Vyy = ws[OFF_TYY] * ic2 - 2.f * ws[OFF_SUMS + 4] * ic3 + Sy * Sy * ic4;
        float dcor = sqrtf(fmaxf(Vxy, EPS_F)) /
                     (sqrtf(fmaxf(Vxx, EPS_F)) * sqrtf(fmaxf(Vyy, EPS_F)));
        out[0] = bce + dcor;
    }
}

extern "C" void kernel_launch(void* const* d_in, const int* in_sizes, int n_in,
                              void* d_out, int out_size, void* d_ws, size_t ws_size,
                              hipStream_t stream) {
    const float* x = (const float*)d_in[0];   // inputs  [8192]
    const float* t = (const float*)d_in[1];   // targets [8192]
    const float* s = (const float*)d_in[2];   // spectators [8192]
    float* ws = (float*)d_ws;
    float* out = (float*)d_out;

    hipMemsetAsync(d_ws, 0, ZERO_SCALARS * sizeof(float), stream);
    k_stage1<<<NTOT / 256, 256, 0, stream>>>(x, t, s, ws);
    k_pairs<<<PAIR_GRID, 256, 0, stream>>>(ws);
    k_final<<<FIN_GRID, 256, 0, stream>>>(ws, out);
}

// Round 11
// 86.475 us; speedup vs baseline: 2.5869x; 1.1843x over previous
//
#include <hip/hip_runtime.h>
#include <math.h>

// Problem constants (match reference)
#define NTOT 8192
#define THRESH 0.5f
#define EPS_F 1e-8f

#define NSEG 32                 // i-segments == stage1 blocks
#define SEGSZ 256
#define NJG 8                   // j-groups in k_pairs
#define SEG_PER_JG (NSEG / NJG) // 4 segments per j-group

// ws layout (float index). No memset needed: every word is plain-stored
// in-stream before any read/atomic of it.
#define OFF_CNT 0               // [32] unsigned per-segment counts
#define OFF_BCEP 32             // [32] float per-block BCE partials
#define OFF_TXY 64              // zeroed by stage1 block 0
#define OFF_TXX 65
#define OFF_TYY 66
#define OFF_SUMS 67             // 5 floats: sx, sy, sxy, sxx, syy
#define OFF_DONE 72             // unsigned ticket
#define OFF_PSS 128             // float2[NTOT] segmented-compacted (p,s)
#define OFF_RXP (OFF_PSS + 2 * NTOT)      // [NJG][NTOT] row-x partials
#define OFF_RYP (OFF_RXP + NJG * NTOT)    // [NJG][NTOT] row-y partials

__device__ inline float wave_reduce(float v) {
#pragma unroll
    for (int o = 32; o > 0; o >>= 1) v += __shfl_down(v, o, 64);
    return v;
}

// Pass 1: BCE partials + deterministic block-segmented compaction.
// Zero global atomics; zero pre-zeroed-memory requirements.
__global__ void __launch_bounds__(256) k_stage1(const float* __restrict__ x,
                                                const float* __restrict__ t,
                                                const float* __restrict__ s,
                                                float* __restrict__ ws) {
    __shared__ unsigned wcnt[4];
    __shared__ float wbce[4];
    const int tid = threadIdx.x, b = blockIdx.x;
    const int lane = tid & 63, w = tid >> 6;
    // Block 0 zeroes accumulator scalars [64,80) consumed in later dispatches.
    if (b == 0 && tid < 16) ws[OFF_TXY + tid] = 0.f;

    const int i = b * SEGSZ + tid;
    float xi = x[i], ti = t[i], si = s[i];
    float bce = fmaxf(xi, 0.f) - xi * ti + log1pf(expf(-fabsf(xi)));
    bool sel = (si >= THRESH);
    unsigned long long ball = __ballot(sel);
    unsigned pre = __popcll(ball & ((1ull << lane) - 1ull));
    if (lane == 0) wcnt[w] = __popcll(ball);
    float bsum = wave_reduce(bce);
    if (lane == 0) wbce[w] = bsum;
    __syncthreads();
    unsigned off = 0;
#pragma unroll
    for (int k = 0; k < 4; ++k)
        if (k < w) off += wcnt[k];
    if (sel) {
        float p = 1.f / (1.f + expf(-xi));
        ((float2*)(ws + OFF_PSS))[b * SEGSZ + off + pre] = make_float2(p, si);
    }
    if (tid == 0) {
        ((unsigned*)(ws + OFF_CNT))[b] = wcnt[0] + wcnt[1] + wcnt[2] + wcnt[3];
        ws[OFF_BCEP + b] = wbce[0] + wbce[1] + wbce[2] + wbce[3];
    }
}

// Pass 2: all-pairs. Block = (i-segment ib) x (j-group jg of 4 segments).
// Rows: exclusive plain stores. T-sums: 3 atomics/block (zeroed in stage1).
__global__ void __launch_bounds__(256) k_pairs(float* __restrict__ ws) {
    __shared__ float2 pjs[SEGSZ];
    __shared__ float accs[3];
    const int tid = threadIdx.x;
    const int ib = blockIdx.x & (NSEG - 1);
    const int jg = blockIdx.x >> 5;
    const unsigned* cnt = (const unsigned*)(ws + OFF_CNT);
    const float2* pss = (const float2*)(ws + OFF_PSS);
    const int ci = (int)cnt[ib];
    const bool valid = tid < ci;
    float2 me = valid ? pss[ib * SEGSZ + tid] : make_float2(0.f, 0.f);
    if (tid < 3) accs[tid] = 0.f;

    float rsx = 0.f, rsy = 0.f, t_xy = 0.f, t_xx = 0.f, t_yy = 0.f;
    for (int k = 0; k < SEG_PER_JG; ++k) {
        const int seg = jg * SEG_PER_JG + k;
        const int cj = (int)cnt[seg];
        __syncthreads();                       // pjs (and accs) settled / free
        if (tid < cj) pjs[tid] = pss[seg * SEGSZ + tid];
        __syncthreads();
        if (valid) {
#pragma unroll 8
            for (int j = 0; j < cj; ++j) {
                float2 v = pjs[j];             // ds_read_b64 broadcast
                float d1 = me.x - v.x;
                float d2 = me.y - v.y;
                float a1 = fabsf(d1);          // abs input modifier
                float a2 = fabsf(d2);
                rsx += a1;
                rsy += a2;
                t_xy = fmaf(a1, a2, t_xy);
                t_xx = fmaf(d1, d1, t_xx);     // |d|^2 == d^2
                t_yy = fmaf(d2, d2, t_yy);
            }
        }
    }
    // Exclusive-writer stores (invalid lanes store 0 so k_final reads are clean).
    const int i = ib * SEGSZ + tid;
    ws[OFF_RXP + jg * NTOT + i] = rsx;
    ws[OFF_RYP + jg * NTOT + i] = rsy;

    t_xy = wave_reduce(t_xy);
    t_xx = wave_reduce(t_xx);
    t_yy = wave_reduce(t_yy);
    if ((tid & 63) == 0) {
        atomicAdd(&accs[0], t_xy);
        atomicAdd(&accs[1], t_xx);
        atomicAdd(&accs[2], t_yy);
    }
    __syncthreads();
    if (tid == 0) {
        atomicAdd(ws + OFF_TXY, accs[0]);
        atomicAdd(ws + OFF_TXX, accs[1]);
        atomicAdd(ws + OFF_TYY, accs[2]);
    }
}

// Pass 3: reduce 8-way row partials; last-done block assembles output.
__global__ void __launch_bounds__(256) k_final(float* __restrict__ ws,
                                               float* __restrict__ out) {
    __shared__ float accs[5];
    __shared__ unsigned lastf;
    const int tid = threadIdx.x, b = blockIdx.x;
    const unsigned* cnt = (const unsigned*)(ws + OFF_CNT);
    const int ci = (int)cnt[b];
    const int i = b * SEGSZ + tid;
    float sx = 0, sy = 0, sxy = 0, sxx = 0, syy = 0;
    if (tid < ci) {
        float rx = 0.f, ry = 0.f;
#pragma unroll
        for (int jg = 0; jg < NJG; ++jg) {     // coalesced, L2-resident
            rx += ws[OFF_RXP + jg * NTOT + i];
            ry += ws[OFF_RYP + jg * NTOT + i];
        }
        sx = rx;
        sy = ry;
        sxy = rx * ry;
        sxx = rx * rx;
        syy = ry * ry;
    }
    sx = wave_reduce(sx);
    sy = wave_reduce(sy);
    sxy = wave_reduce(sxy);
    sxx = wave_reduce(sxx);
    syy = wave_reduce(syy);
    if (tid < 5) accs[tid] = 0.f;
    __syncthreads();
    if ((tid & 63) == 0) {
        atomicAdd(&accs[0], sx);
        atomicAdd(&accs[1], sy);
        atomicAdd(&accs[2], sxy);
        atomicAdd(&accs[3], sxx);
        atomicAdd(&accs[4], syy);
    }
    __syncthreads();
    if (tid == 0) {
        atomicAdd(ws + OFF_SUMS + 0, accs[0]);
        atomicAdd(ws + OFF_SUMS + 1, accs[1]);
        atomicAdd(ws + OFF_SUMS + 2, accs[2]);
        atomicAdd(ws + OFF_SUMS + 3, accs[3]);
        atomicAdd(ws + OFF_SUMS + 4, accs[4]);
    }
    __threadfence();                           // release (32 blocks)
    if (tid == 0) {
        unsigned prev = atomicAdd((unsigned*)(ws + OFF_DONE), 1u);
        lastf = (prev == NSEG - 1) ? 1u : 0u;
    }
    __syncthreads();
    if (!lastf) return;
    __threadfence();                           // acquire
    if (tid == 0) {
        unsigned c = 0;
        float bsum = 0.f;
        for (int k = 0; k < NSEG; ++k) {
            c += cnt[k];
            bsum += ws[OFF_BCEP + k];
        }
        float bce = bsum / (float)NTOT;
        if (c == 0) { out[0] = bce; return; }
        float cf = (float)c;
        float ic2 = 1.f / (cf * cf);
        float ic3 = ic2 / cf;
        float ic4 = ic2 * ic2;
        float Sx = ws[OFF_SUMS + 0], Sy = ws[OFF_SUMS + 1];
        // masked mean-products via the dCov expansion identity
        float Vxy = ws[OFF_TXY] * ic2 - 2.f * ws[OFF_SUMS + 2] * ic3 + Sx * Sy * ic4;
        float Vxx = ws[OFF_TXX] * ic2 - 2.f * ws[OFF_SUMS + 3] * ic3 + Sx * Sx * ic4;
        float Vyy = ws[OFF_TYY] * ic2 - 2.f * ws[OFF_SUMS + 4] * ic3 + Sy * Sy * ic4;
        float dcor = sqrtf(fmaxf(Vxy, EPS_F)) /
                     (sqrtf(fmaxf(Vxx, EPS_F)) * sqrtf(fmaxf(Vyy, EPS_F)));
        out[0] = bce + dcor;
    }
}

extern "C" void kernel_launch(void* const* d_in, const int* in_sizes, int n_in,
                              void* d_out, int out_size, void* d_ws, size_t ws_size,
                              hipStream_t stream) {
    const float* x = (const float*)d_in[0];   // inputs  [8192]
    const float* t = (const float*)d_in[1];   // targets [8192]
    const float* s = (const float*)d_in[2];   // spectators [8192]
    float* ws = (float*)d_ws;
    float* out = (float*)d_out;

    k_stage1<<<NSEG, SEGSZ, 0, stream>>>(x, t, s, ws);
    k_pairs<<<NSEG * NJG, SEGSZ, 0, stream>>>(ws);
    k_final<<<NSEG, SEGSZ, 0, stream>>>(ws, out);
}

// Round 13
// 84.019 us; speedup vs baseline: 2.6625x; 1.0292x over previous
//
#include <hip/hip_runtime.h>
#include <math.h>

// Problem constants (match reference)
#define NTOT 8192
#define THRESH 0.5f
#define EPS_F 1e-8f

#define NSEG 32                 // i-segments
#define SEGSZ 256
#define NJG 8                   // j-groups
#define SEG_PER_JG (NSEG / NJG) // 4 j-segments per j-group
#define NBLK (NSEG * NJG)       // 256 blocks in k_main

// ws layout (float index). Every word is plain-stored before any read;
// zero global atomics; zero memset; zero fences.
#define OFF_CNT 0                         // [32] unsigned per-segment counts
#define OFF_BCEP 32                       // [32] float per-segment BCE partials
#define OFF_TP 64                         // [256][3] per-block T partials
#define OFF_RXP (OFF_TP + 3 * NBLK)       // [NJG][NTOT] row-x partials
#define OFF_RYP (OFF_RXP + NJG * NTOT)    // [NJG][NTOT] row-y partials

__device__ inline float wave_reduce(float v) {
#pragma unroll
    for (int o = 32; o > 0; o >>= 1) v += __shfl_down(v, o, 64);
    return v;
}

// Pass 1 of 2: self-contained. Block (ib, jg) recomputes compaction locally
// (deterministic ballot/popcount -> bit-identical across blocks), does the
// pair loop vs its 4 j-segments, and writes ONLY exclusive plain stores.
__global__ void __launch_bounds__(256) k_main(const float* __restrict__ x,
                                              const float* __restrict__ t,
                                              const float* __restrict__ s,
                                              float* __restrict__ ws) {
    __shared__ float2 pjs[SEGSZ];
    __shared__ float2 mis[SEGSZ];
    __shared__ unsigned wcnt[4];
    __shared__ float wred[4];
    __shared__ float accs[3];
    const int tid = threadIdx.x;
    const int lane = tid & 63, w = tid >> 6;
    const int ib = blockIdx.x & (NSEG - 1);
    const int jg = blockIdx.x >> 5;

    // ---- compact own i-segment into mis (and BCE for jg==0 blocks) ----
    const int gi = ib * SEGSZ + tid;
    const float xi = x[gi], si = s[gi];
    const bool sel = (si >= THRESH);
    unsigned long long ball = __ballot(sel);
    unsigned pre = __popcll(ball & ((1ull << lane) - 1ull));
    if (lane == 0) wcnt[w] = (unsigned)__popcll(ball);
    if (tid < 3) accs[tid] = 0.f;
    if (jg == 0) {
        float ti = t[gi];
        float bce = fmaxf(xi, 0.f) - xi * ti + log1pf(expf(-fabsf(xi)));
        bce = wave_reduce(bce);
        if (lane == 0) wred[w] = bce;
    }
    __syncthreads();
    unsigned off = 0;
#pragma unroll
    for (int k = 0; k < 4; ++k)
        if (k < w) off += wcnt[k];
    const int ci = (int)(wcnt[0] + wcnt[1] + wcnt[2] + wcnt[3]);
    if (sel) mis[off + pre] = make_float2(1.f / (1.f + expf(-xi)), si);
    if (jg == 0 && tid == 0) {
        ((unsigned*)(ws + OFF_CNT))[ib] = (unsigned)ci;
        ws[OFF_BCEP + ib] = wred[0] + wred[1] + wred[2] + wred[3];
    }
    __syncthreads();                        // mis ready; wcnt reads done
    const bool valid = tid < ci;
    float2 me = mis[tid];                   // uninit beyond ci: gated by valid

    // ---- pair loop over 4 j-segments, each compacted on the fly ----
    float rsx = 0.f, rsy = 0.f, txy = 0.f, txx = 0.f, tyy = 0.f;
    for (int k = 0; k < SEG_PER_JG; ++k) {
        const int seg = jg * SEG_PER_JG + k;
        const int gj = seg * SEGSZ + tid;
        const float xj = x[gj], sj = s[gj];
        const bool selj = (sj >= THRESH);
        unsigned long long bj = __ballot(selj);
        unsigned prej = __popcll(bj & ((1ull << lane) - 1ull));
        if (lane == 0) wcnt[w] = (unsigned)__popcll(bj);
        __syncthreads();                    // wcnt ready; prev pjs reads done
        unsigned offj = 0;
#pragma unroll
        for (int q = 0; q < 4; ++q)
            if (q < w) offj += wcnt[q];
        const int cj = (int)(wcnt[0] + wcnt[1] + wcnt[2] + wcnt[3]);
        if (selj) pjs[offj + prej] = make_float2(1.f / (1.f + expf(-xj)), sj);
        __syncthreads();                    // pjs ready; wcnt reads done
        if (valid) {
#pragma unroll 8
            for (int j = 0; j < cj; ++j) {
                float2 v = pjs[j];          // ds_read_b64 broadcast
                float d1 = me.x - v.x;
                float d2 = me.y - v.y;
                float a1 = fabsf(d1);       // abs input modifier
                float a2 = fabsf(d2);
                rsx += a1;
                rsy += a2;
                txy = fmaf(a1, a2, txy);
                txx = fmaf(d1, d1, txx);    // |d|^2 == d^2
                tyy = fmaf(d2, d2, tyy);
            }
        }
    }

    // Exclusive-writer stores (invalid lanes store 0: clean for k_final).
    ws[OFF_RXP + jg * NTOT + gi] = rsx;
    ws[OFF_RYP + jg * NTOT + gi] = rsy;

    txy = wave_reduce(txy);
    txx = wave_reduce(txx);
    tyy = wave_reduce(tyy);
    if (lane == 0) {                        // LDS atomics only
        atomicAdd(&accs[0], txy);
        atomicAdd(&accs[1], txx);
        atomicAdd(&accs[2], tyy);
    }
    __syncthreads();
    if (tid == 0) {                         // exclusive per-block store
        float* tp = ws + OFF_TP + blockIdx.x * 3;
        tp[0] = accs[0];
        tp[1] = accs[1];
        tp[2] = accs[2];
    }
}

// Pass 2 of 2: ONE block reduces all partials and assembles the loss.
__global__ void __launch_bounds__(256) k_final(const float* __restrict__ ws,
                                               float* __restrict__ out) {
    __shared__ float red[4][12];
    const int tid = threadIdx.x;
    const int lane = tid & 63, w = tid >> 6;

    // Row partial reduction (rows >= c have zero partials -> contribute 0).
    float sx = 0, sy = 0, sxy = 0, sxx = 0, syy = 0;
    for (int i = tid; i < NTOT; i += 256) {
        float rx = 0.f, ry = 0.f;
#pragma unroll
        for (int jg = 0; jg < NJG; ++jg) {  // coalesced, L2-resident
            rx += ws[OFF_RXP + jg * NTOT + i];
            ry += ws[OFF_RYP + jg * NTOT + i];
        }
        sx += rx;
        sy += ry;
        sxy = fmaf(rx, ry, sxy);
        sxx = fmaf(rx, rx, sxx);
        syy = fmaf(ry, ry, syy);
    }
    // Per-block T partials: thread tid owns k_main block tid.
    const float* tp = ws + OFF_TP + tid * 3;
    float txy = tp[0], txx = tp[1], tyy = tp[2];
    // BCE partials + counts (tid < 32, all within wave 0; others contribute 0).
    float bcep = 0.f, cp = 0.f;
    if (tid < NSEG) {
        bcep = ws[OFF_BCEP + tid];
        cp = (float)((const unsigned*)(ws + OFF_CNT))[tid];
    }

    float v0 = wave_reduce(sx), v1 = wave_reduce(sy), v2 = wave_reduce(sxy);
    float v3 = wave_reduce(sxx), v4 = wave_reduce(syy);
    float v5 = wave_reduce(txy), v6 = wave_reduce(txx), v7 = wave_reduce(tyy);
    float v8 = wave_reduce(bcep), v9 = wave_reduce(cp);
    if (lane == 0) {
        red[w][0] = v0; red[w][1] = v1; red[w][2] = v2; red[w][3] = v3;
        red[w][4] = v4; red[w][5] = v5; red[w][6] = v6; red[w][7] = v7;
        red[w][8] = v8; red[w][9] = v9;
    }
    __syncthreads();
    if (tid == 0) {
        float q[10];
#pragma unroll
        for (int k = 0; k < 10; ++k)
            q[k] = red[0][k] + red[1][k] + red[2][k] + red[3][k];
        float bce = q[8] / (float)NTOT;
        float c = q[9];                      // exact: integer <= 8192
        if (c == 0.f) { out[0] = bce; return; }
        float ic2 = 1.f / (c * c);
        float ic3 = ic2 / c;
        float ic4 = ic2 * ic2;
        // masked mean-products via the dCov expansion identity
        float Vxy = q[5] * ic2 - 2.f * q[2] * ic3 + q[0] * q[1] * ic4;
        float Vxx = q[6] * ic2 - 2.f * q[3] * ic3 + q[0] * q[0] * ic4;
        float Vyy = q[7] * ic2 - 2.f * q[4] * ic3 + q[1] * q[1] * ic4;
        float dcor = sqrtf(fmaxf(Vxy, EPS_F)) /
                     (sqrtf(fmaxf(Vxx, EPS_F)) * sqrtf(fmaxf(Vyy, EPS_F)));
        out[0] = bce + dcor;
    }
}

extern "C" void kernel_launch(void* const* d_in, const int* in_sizes, int n_in,
                              void* d_out, int out_size, void* d_ws, size_t ws_size,
                              hipStream_t stream) {
    const float* x = (const float*)d_in[0];   // inputs  [8192]
    const float* t = (const float*)d_in[1];   // targets [8192]
    const float* s = (const float*)d_in[2];   // spectators [8192]
    float* ws = (float*)d_ws;
    float* out = (float*)d_out;

    k_main<<<NBLK, SEGSZ, 0, stream>>>(x, t, s, ws);
    k_final<<<1, SEGSZ, 0, stream>>>(ws, out);
}

// Round 20
// 73.478 us; speedup vs baseline: 3.0445x; 1.1435x over previous
//
#include <hip/hip_runtime.h>
#include <math.h>

// Problem constants (match reference)
#define NTOT 8192
#define THRESH 0.5f
#define EPS_F 1e-8f

#define NSEG 32                 // i-segments of 256
#define SEGSZ 256
#define NJG 16                  // j-groups
#define SEGS_PER_JG 2           // 2 j-segments (512 raw cols) per j-group
#define NBLK (NSEG * NJG)       // 512 blocks in k_main -> 2 blocks/CU
#define FINB 32                 // k_final blocks

// ws layout (float index). Every word is plain-stored in-stream before any
// read; zero global atomics in the data path; zero memsets.
#define OFF_CNT 0                          // [32] unsigned per-segment counts
#define OFF_BCEP 32                        // [32] float per-segment BCE partials
#define OFF_DONE 64                        // unsigned ticket (zeroed by k_main blk0)
#define OFF_FP 72                          // [32][5] k_final block partials
#define OFF_TP 256                         // [512][3] per-block T partials
#define OFF_RXP 2048                       // [NJG][NTOT] row-x partials
#define OFF_RYP (OFF_RXP + NJG * NTOT)     // [NJG][NTOT] row-y partials

__device__ inline float wave_reduce(float v) {
#pragma unroll
    for (int o = 32; o > 0; o >>= 1) v += __shfl_down(v, o, 64);
    return v;
}

// Pass 1: block (ib, jg) compacts locally (deterministic ballot/popcount) and
// does pairs of segment ib's rows vs 2 j-segments. Exclusive plain stores only.
__global__ void __launch_bounds__(256) k_main(const float* __restrict__ x,
                                              const float* __restrict__ t,
                                              const float* __restrict__ s,
                                              float* __restrict__ ws) {
    __shared__ float2 pjs[SEGSZ];
    __shared__ float2 mis[SEGSZ];
    __shared__ unsigned wcnt[4];
    __shared__ float wred[4];
    __shared__ float accs[3];
    const int tid = threadIdx.x;
    const int lane = tid & 63, w = tid >> 6;
    const int ib = blockIdx.x & (NSEG - 1);
    const int jg = blockIdx.x >> 5;          // / NSEG
    if (blockIdx.x == 0 && tid == 0) ((unsigned*)(ws + OFF_DONE))[0] = 0u;

    // ---- compact own i-segment into mis (BCE on jg==0 blocks) ----
    const int gi = ib * SEGSZ + tid;
    const float xi = x[gi], si = s[gi];
    const bool sel = (si >= THRESH);
    unsigned long long ball = __ballot(sel);
    unsigned pre = __popcll(ball & ((1ull << lane) - 1ull));
    if (lane == 0) wcnt[w] = (unsigned)__popcll(ball);
    if (tid < 3) accs[tid] = 0.f;
    if (jg == 0) {
        float ti = t[gi];
        float bce = fmaxf(xi, 0.f) - xi * ti + log1pf(expf(-fabsf(xi)));
        bce = wave_reduce(bce);
        if (lane == 0) wred[w] = bce;
    }
    __syncthreads();
    unsigned off = 0;
#pragma unroll
    for (int k = 0; k < 4; ++k)
        if (k < w) off += wcnt[k];
    const int ci = (int)(wcnt[0] + wcnt[1] + wcnt[2] + wcnt[3]);
    if (sel) mis[off + pre] = make_float2(1.f / (1.f + expf(-xi)), si);
    if (jg == 0 && tid == 0) {
        ((unsigned*)(ws + OFF_CNT))[ib] = (unsigned)ci;
        ws[OFF_BCEP + ib] = wred[0] + wred[1] + wred[2] + wred[3];
    }
    __syncthreads();                         // mis ready; wcnt reads done
    const bool valid = tid < ci;
    float2 me = mis[tid];                    // beyond ci: gated by valid

    // ---- pair loop over 2 j-segments, compacted on the fly ----
    float rsx = 0.f, rsy = 0.f, txy = 0.f, txx = 0.f, tyy = 0.f;
    for (int k = 0; k < SEGS_PER_JG; ++k) {
        const int seg = jg * SEGS_PER_JG + k;
        const int gj = seg * SEGSZ + tid;
        const float xj = x[gj], sj = s[gj];
        const bool selj = (sj >= THRESH);
        unsigned long long bj = __ballot(selj);
        unsigned prej = __popcll(bj & ((1ull << lane) - 1ull));
        if (lane == 0) wcnt[w] = (unsigned)__popcll(bj);
        __syncthreads();                     // wcnt ready; prev pjs reads done
        unsigned offj = 0;
#pragma unroll
        for (int q = 0; q < 4; ++q)
            if (q < w) offj += wcnt[q];
        const int cj = (int)(wcnt[0] + wcnt[1] + wcnt[2] + wcnt[3]);
        if (selj) pjs[offj + prej] = make_float2(1.f / (1.f + expf(-xj)), sj);
        __syncthreads();                     // pjs ready; wcnt reads done
        if (valid) {
#pragma unroll 8
            for (int j = 0; j < cj; ++j) {
                float2 v = pjs[j];           // ds_read_b64 broadcast
                float d1 = me.x - v.x;
                float d2 = me.y - v.y;
                float a1 = fabsf(d1);        // abs input modifier
                float a2 = fabsf(d2);
                rsx += a1;
                rsy += a2;
                txy = fmaf(a1, a2, txy);
                txx = fmaf(d1, d1, txx);     // |d|^2 == d^2
                tyy = fmaf(d2, d2, tyy);
            }
        }
    }

    // Exclusive-writer stores (invalid lanes store 0: clean for k_final).
    ws[OFF_RXP + jg * NTOT + gi] = rsx;
    ws[OFF_RYP + jg * NTOT + gi] = rsy;

    txy = wave_reduce(txy);
    txx = wave_reduce(txx);
    tyy = wave_reduce(tyy);
    if (lane == 0) {                         // LDS atomics only
        atomicAdd(&accs[0], txy);
        atomicAdd(&accs[1], txx);
        atomicAdd(&accs[2], tyy);
    }
    __syncthreads();
    if (tid == 0) {                          // exclusive per-block store
        float* tp = ws + OFF_TP + blockIdx.x * 3;
        tp[0] = accs[0];
        tp[1] = accs[1];
        tp[2] = accs[2];
    }
}

// Pass 2: 32 blocks, thread = row; coalesced 16-way fan-in; last-done block
// (fenced ticket over 32 blocks) assembles the loss.
__global__ void __launch_bounds__(256) k_final(float* __restrict__ ws,
                                               float* __restrict__ out) {
    __shared__ float red[4][12];
    __shared__ unsigned lastf;
    const int tid = threadIdx.x, b = blockIdx.x;
    const int lane = tid & 63, w = tid >> 6;

    const int row = b * SEGSZ + tid;
    float rx = 0.f, ry = 0.f;
#pragma unroll
    for (int jg = 0; jg < NJG; ++jg) {       // coalesced, L2-resident
        rx += ws[OFF_RXP + jg * NTOT + row];
        ry += ws[OFF_RYP + jg * NTOT + row];
    }
    float v0 = wave_reduce(rx);
    float v1 = wave_reduce(ry);
    float v2 = wave_reduce(rx * ry);
    float v3 = wave_reduce(rx * rx);
    float v4 = wave_reduce(ry * ry);
    if (lane == 0) {
        red[w][0] = v0; red[w][1] = v1; red[w][2] = v2;
        red[w][3] = v3; red[w][4] = v4;
    }
    __syncthreads();
    if (tid == 0) {
        float* fp = ws + OFF_FP + b * 5;     // exclusive store
#pragma unroll
        for (int q = 0; q < 5; ++q)
            fp[q] = red[0][q] + red[1][q] + red[2][q] + red[3][q];
    }
    __threadfence();                         // release
    if (tid == 0) {
        unsigned prev = atomicAdd((unsigned*)(ws + OFF_DONE), 1u);
        lastf = (prev == FINB - 1) ? 1u : 0u;
    }
    __syncthreads();
    if (!lastf) return;
    __threadfence();                         // acquire

    // ---- last block: gather everything ----
    const float* tp0 = ws + OFF_TP + tid * 3;
    const float* tp1 = ws + OFF_TP + (tid + 256) * 3;
    float t5 = tp0[0] + tp1[0];
    float t6 = tp0[1] + tp1[1];
    float t7 = tp0[2] + tp1[2];
    float f0 = 0, f1 = 0, f2 = 0, f3 = 0, f4 = 0, bcep = 0, cp = 0;
    if (tid < FINB) {
        const float* fp = ws + OFF_FP + tid * 5;
        f0 = fp[0]; f1 = fp[1]; f2 = fp[2]; f3 = fp[3]; f4 = fp[4];
        bcep = ws[OFF_BCEP + tid];
        cp = (float)((const unsigned*)(ws + OFF_CNT))[tid];
    }
    float q0 = wave_reduce(f0), q1 = wave_reduce(f1), q2 = wave_reduce(f2);
    float q3 = wave_reduce(f3), q4 = wave_reduce(f4);
    float q5 = wave_reduce(t5), q6 = wave_reduce(t6), q7 = wave_reduce(t7);
    float q8 = wave_reduce(bcep), q9 = wave_reduce(cp);
    __syncthreads();                         // red[] free for reuse
    if (lane == 0) {
        red[w][0] = q0; red[w][1] = q1; red[w][2] = q2; red[w][3] = q3;
        red[w][4] = q4; red[w][5] = q5; red[w][6] = q6; red[w][7] = q7;
        red[w][8] = q8; red[w][9] = q9;
    }
    __syncthreads();
    if (tid == 0) {
        float q[10];
#pragma unroll
        for (int k = 0; k < 10; ++k)
            q[k] = red[0][k] + red[1][k] + red[2][k] + red[3][k];
        float bce = q[8] / (float)NTOT;
        float c = q[9];                      // exact: integer <= 8192
        if (c == 0.f) { out[0] = bce; return; }
        float ic2 = 1.f / (c * c);
        float ic3 = ic2 / c;
        float ic4 = ic2 * ic2;
        // masked mean-products via the dCov expansion identity
        float Vxy = q[5] * ic2 - 2.f * q[2] * ic3 + q[0] * q[1] * ic4;
        float Vxx = q[6] * ic2 - 2.f * q[3] * ic3 + q[0] * q[0] * ic4;
        float Vyy = q[7] * ic2 - 2.f * q[4] * ic3 + q[1] * q[1] * ic4;
        float dcor = sqrtf(fmaxf(Vxy, EPS_F)) /
                     (sqrtf(fmaxf(Vxx, EPS_F)) * sqrtf(fmaxf(Vyy, EPS_F)));
        out[0] = bce + dcor;
    }
}

extern "C" void kernel_launch(void* const* d_in, const int* in_sizes, int n_in,
                              void* d_out, int out_size, void* d_ws, size_t ws_size,
                              hipStream_t stream) {
    const float* x = (const float*)d_in[0];   // inputs  [8192]
    const float* t = (const float*)d_in[1];   // targets [8192]
    const float* s = (const float*)d_in[2];   // spectators [8192]
    float* ws = (float*)d_ws;
    float* out = (float*)d_out;

    k_main<<<NBLK, SEGSZ, 0, stream>>>(x, t, s, ws);
    k_final<<<FINB, SEGSZ, 0, stream>>>(ws, out);
}